// Round 6
// baseline (278.297 us; speedup 1.0000x reference)
//
#include <hip/hip_runtime.h>
#include <math.h>

#define N_ 16
#define T_ 8192
#define C_ 128
#define K_ 64

#define BPN 128   // blocks per n
#define TPB 64    // t per block
#define TILE 8    // t per wave-tile
#define SUP 32    // t per super-tile (4 waves x TILE)

// ws layout in floats
#define WS_VLAD 0              // N*K*C = 131072
#define WS_ASUM 131072         // N*K
#define WS_GSUM 132096         // N
#define WS_ZEND 132608
#define WS_RNORM 132608        // N*T floats -> ends at 263680
#define WS_W2F   263680        // 4096 floats (8192 bf16 = w2 fragment table)
#define WS_P1    267776        // 512 floats (wa|wb|wc|sb, each [128])

typedef __attribute__((ext_vector_type(8))) short short8;
typedef __attribute__((ext_vector_type(4))) float f32x4;

__device__ __forceinline__ uint bfr(float f) {          // fp32 -> bf16 (RNE)
    uint u = __float_as_uint(f);
    return (u + 0x7fffu + ((u >> 16) & 1u)) >> 16;
}
__device__ __forceinline__ uint pack2(float lo, float hi) {
    return bfr(lo) | (bfr(hi) << 16);
}
__device__ __forceinline__ float bflo(uint h) { return __uint_as_float(h << 16); }

__global__ void zero_ws(float* ws) {
    int i = blockIdx.x * 256 + threadIdx.x;
    if (i < WS_ZEND) ws[i] = 0.0f;
}

// Precompute constant tables, laid out for coalesced loads in main_k.
__global__ void setup_k(const float* __restrict__ conv1_w,
                        const float* __restrict__ bn1_g, const float* __restrict__ bn1_b,
                        const float* __restrict__ bn1_m, const float* __restrict__ bn1_v,
                        const float* __restrict__ conv2_w,
                        const float* __restrict__ bn2_g, const float* __restrict__ bn2_v,
                        float* __restrict__ ws) {
    const int tid = threadIdx.x;
    // w2 fragment table: idx = ((m*4+q)*64 + lane)*8 + j
    ushort* w2t = (ushort*)(ws + WS_W2F);
    for (int idx = tid; idx < 8192; idx += 256) {
        int j = idx & 7;
        int lane = (idx >> 3) & 63;
        int mq = idx >> 9;                  // 0..15
        int m = mq >> 2, q = mq & 3;
        int fr = lane & 15, fg = lane >> 4;
        int k = m * 16 + fr;
        float sck = bn2_g[k] * rsqrtf(bn2_v[k] + 1e-5f);
        float v = conv2_w[k * C_ + q * 32 + fg * 8 + j] * sck;
        w2t[idx] = (ushort)bfr(v);
    }
    // conv1/bn1 folded params, [param][c]
    for (int c = tid; c < C_; c += 256) {
        float s1 = bn1_g[c] * rsqrtf(bn1_v[c] + 1e-5f);
        ws[WS_P1 + c]       = conv1_w[c * 9 + 1] * s1;
        ws[WS_P1 + 128 + c] = conv1_w[c * 9 + 4] * s1;
        ws[WS_P1 + 256 + c] = conv1_w[c * 9 + 7] * s1;
        ws[WS_P1 + 384 + c] = bn1_b[c] - bn1_m[c] * s1;
    }
}

// 1 / max(||x[n,t,:]||, 1e-12), one wave per (n,t) row
__global__ void rnorm_k(const float* __restrict__ x, float* __restrict__ ws) {
    int row = blockIdx.x * 4 + (threadIdx.x >> 6);
    int lane = threadIdx.x & 63;
    const float* xr = x + (size_t)row * C_;
    float a = xr[lane], b = xr[lane + 64];
    float ss = a * a + b * b;
#pragma unroll
    for (int m = 1; m < 64; m <<= 1) ss += __shfl_xor(ss, m, 64);
    if (lane == 0) ws[WS_RNORM + row] = 1.0f / fmaxf(sqrtf(ss), 1e-12f);
}

// Fused: normalize -> dwconv3+bn1+relu -> logits (MFMA) -> bn2+relu+mask
// -> softmax -> vlad GEMM (MFMA, bf16 a/xn, fp32 acc) + asum.
__global__ __launch_bounds__(256, 4) void main_k(
    const float* __restrict__ x,
    const float* __restrict__ conv2_b,
    const float* __restrict__ bn2_g, const float* __restrict__ bn2_b,
    const float* __restrict__ bn2_m, const float* __restrict__ bn2_v,
    const int* __restrict__ length,
    float* __restrict__ ws) {

    // h: per-wave [8t][136c-pad] bf16 (272B rows)
    __shared__ __align__(16) ushort h_s[4][TILE * 136];      // 8704 B
    // xn: [128c][80B rows]: 4 data chunks of 16B (8t bf16) + 1 pad chunk
    __shared__ __align__(16) char xnb[C_ * 80];              // 10240 B
    // a:  [64k][80B rows]: 4 data chunks + pad
    __shared__ __align__(16) char ab[K_ * 80];               // 5120 B
    __shared__ float rn_lds[TPB + 2];

    const int tid = threadIdx.x;
    const int lane = tid & 63;
    const int w = tid >> 6;
    const int fr = lane & 15, fg = lane >> 4;
    const int n = blockIdx.x >> 7;                 // / BPN
    const int tb = (blockIdx.x & (BPN - 1)) * TPB;
    const float* xb = x + (size_t)n * T_ * C_;
    const float* rng = ws + WS_RNORM + (size_t)n * T_;
    const int L = length[n];

    for (int i = tid; i < TPB + 2; i += 256) {
        int t = tb - 1 + i;
        rn_lds[i] = (t >= 0 && t < T_) ? rng[t] : 0.f;
    }

    // conv1/bn1 folded params for the lane's c-pair (c2, c2+1)
    const int c2 = lane * 2;
    float2 wa = *(const float2*)&ws[WS_P1 + c2];
    float2 wb = *(const float2*)&ws[WS_P1 + 128 + c2];
    float2 wc = *(const float2*)&ws[WS_P1 + 256 + c2];
    float2 sb = *(const float2*)&ws[WS_P1 + 384 + c2];

    // w2 A-fragments from precomputed table (coalesced b128 loads)
    const ushort* w2t = (const ushort*)(ws + WS_W2F);
    short8 w2h[4][4];
#pragma unroll
    for (int m = 0; m < 4; ++m)
#pragma unroll
        for (int q = 0; q < 4; ++q)
            w2h[m][q] = *(const short8*)&w2t[((m * 4 + q) * 64 + lane) * 8];

    // bias in softmax register layout: k = m*16 + fg*4 + r
    float sh2r[16];
#pragma unroll
    for (int m = 0; m < 4; ++m)
#pragma unroll
        for (int r = 0; r < 4; ++r) {
            int k = m * 16 + fg * 4 + r;
            float s = bn2_g[k] * rsqrtf(bn2_v[k] + 1e-5f);
            sh2r[m * 4 + r] = s * conv2_b[k] + bn2_b[k] - bn2_m[k] * s;
        }

    f32x4 accB[8];
#pragma unroll
    for (int cb = 0; cb < 8; ++cb) accB[cb] = (f32x4){0.f, 0.f, 0.f, 0.f};
    float asum_reg[16];
#pragma unroll
    for (int i = 0; i < 16; ++i) asum_reg[i] = 0.f;
    int mcnt = 0;

    __syncthreads();

    for (int s = 0; s < TPB / SUP; ++s) {
        const int t0 = tb + s * SUP + w * TILE;
        const bool full = (t0 < L);
        const int tl0 = t0 - tb + s * 0;
        ushort* hw = h_s[w];

        // ---- A1: rolling 3-tap conv along t, lane owns c-pair ----
        {
            float2 xm = {0.f, 0.f};
            if (t0 > 0) xm = *(const float2*)&xb[(size_t)(t0 - 1) * C_ + c2];
            float rm = rn_lds[tl0];
            float xnmx = xm.x * rm, xnmy = xm.y * rm;
            float2 xc = *(const float2*)&xb[(size_t)t0 * C_ + c2];
            float rc = rn_lds[tl0 + 1];
            float xncx = xc.x * rc, xncy = xc.y * rc;
            uint pkx[4], pky[4];
#pragma unroll
            for (int tl = 0; tl < TILE; ++tl) {
                int tn = t0 + tl + 1;
                float2 xp = {0.f, 0.f};
                if (tn < T_) xp = *(const float2*)&xb[(size_t)tn * C_ + c2];
                float rp = rn_lds[tl0 + tl + 2];
                float xnpx = xp.x * rp, xnpy = xp.y * rp;
                if (full) {
                    float hx = fmaxf(0.f, xnmx * wa.x + xncx * wb.x + xnpx * wc.x + sb.x);
                    float hy = fmaxf(0.f, xnmy * wa.y + xncy * wb.y + xnpy * wc.y + sb.y);
                    *(uint*)&hw[tl * 136 + c2] = pack2(hx, hy);
                }
                uint bx = bfr(xncx), by = bfr(xncy);
                if (tl & 1) { pkx[tl >> 1] |= bx << 16; pky[tl >> 1] |= by << 16; }
                else        { pkx[tl >> 1] = bx;        pky[tl >> 1] = by; }
                xnmx = xncx; xnmy = xncy; xncx = xnpx; xncy = xnpy;
            }
            uint4 vx, vy;
            vx.x = pkx[0]; vx.y = pkx[1]; vx.z = pkx[2]; vx.w = pkx[3];
            vy.x = pky[0]; vy.y = pky[1]; vy.z = pky[2]; vy.w = pky[3];
            *(uint4*)&xnb[c2 * 80 + ((w ^ (c2 & 3)) * 16)] = vx;
            *(uint4*)&xnb[(c2 + 1) * 80 + ((w ^ ((c2 + 1) & 3)) * 16)] = vy;
        }

        if (full) {
            // ---- logits MFMA: S[k][t] = sum_c w2'[k][c] h[t][c] ----
            f32x4 accL[4];
#pragma unroll
            for (int m = 0; m < 4; ++m) accL[m] = (f32x4){0.f, 0.f, 0.f, 0.f};
            const ushort* hb = hw + (fr & 7) * 136 + fg * 8;   // fr>=8: broadcast dup
#pragma unroll
            for (int q = 0; q < 4; ++q) {
                short8 hf = *(const short8*)(hb + q * 32);
                accL[0] = __builtin_amdgcn_mfma_f32_16x16x32_bf16(w2h[0][q], hf, accL[0], 0, 0, 0);
                accL[1] = __builtin_amdgcn_mfma_f32_16x16x32_bf16(w2h[1][q], hf, accL[1], 0, 0, 0);
                accL[2] = __builtin_amdgcn_mfma_f32_16x16x32_bf16(w2h[2][q], hf, accL[2], 0, 0, 0);
                accL[3] = __builtin_amdgcn_mfma_f32_16x16x32_bf16(w2h[3][q], hf, accL[3], 0, 0, 0);
            }
            // ---- bn2 + relu + mask + softmax over k (lane column t = t0+fr, fr<8) ----
            if (fr < 8) {
                int t = t0 + fr;
                float v[16];
#pragma unroll
                for (int m = 0; m < 4; ++m)
#pragma unroll
                    for (int r = 0; r < 4; ++r)
                        v[m * 4 + r] = fmaxf(0.f, accL[m][r] + sh2r[m * 4 + r]);
                if (t < L) {
                    float mx = v[0];
#pragma unroll
                    for (int i = 1; i < 16; ++i) mx = fmaxf(mx, v[i]);
                    mx = fmaxf(mx, __shfl_xor(mx, 16, 64));
                    mx = fmaxf(mx, __shfl_xor(mx, 32, 64));
                    float se = 0.f;
#pragma unroll
                    for (int i = 0; i < 16; ++i) { v[i] = __expf(v[i] - mx); se += v[i]; }
                    se += __shfl_xor(se, 16, 64);
                    se += __shfl_xor(se, 32, 64);
                    float inv = 1.0f / se;
#pragma unroll
                    for (int i = 0; i < 16; ++i) v[i] *= inv;
                } else {
#pragma unroll
                    for (int i = 0; i < 16; ++i) v[i] = 0.015625f;
                }
#pragma unroll
                for (int m = 0; m < 4; ++m)
#pragma unroll
                    for (int r = 0; r < 4; ++r) {
                        int k = m * 16 + fg * 4 + r;
                        uint hv = bfr(v[m * 4 + r]);
                        *(ushort*)&ab[k * 80 + ((w ^ (k & 3)) * 16) + fr * 2] = (ushort)hv;
                        asum_reg[m * 4 + r] += bflo(hv);
                    }
            } else {
                // keep shuffle partners alive (fg-reduce partners are fr<8 lanes)
            }
        } else {
            // fully masked tile: a = 1/64 (bf16 exact), all 64 k rows
            uint4 ones;
            ones.x = ones.y = ones.z = ones.w = 0x3C803C80u;
            *(uint4*)&ab[lane * 80 + ((w ^ (lane & 3)) * 16)] = ones;
            mcnt++;
        }
        __syncthreads();

        // ---- phase B: vlad GEMM on MFMA. wave w owns k-block w (K=32 t) ----
        {
            int ar = w * 16 + fr;
            short8 af = *(const short8*)&ab[ar * 80 + ((fg ^ (ar & 3)) * 16)];
#pragma unroll
            for (int cb = 0; cb < 8; ++cb) {
                int cr = cb * 16 + fr;
                short8 bf = *(const short8*)&xnb[cr * 80 + ((fg ^ (cr & 3)) * 16)];
                accB[cb] = __builtin_amdgcn_mfma_f32_16x16x32_bf16(af, bf, accB[cb], 0, 0, 0);
            }
        }
        __syncthreads();
    }

    float* vlad = ws + WS_VLAD + (size_t)n * (K_ * C_);
#pragma unroll
    for (int cb = 0; cb < 8; ++cb)
#pragma unroll
        for (int r = 0; r < 4; ++r)
            atomicAdd(&vlad[(w * 16 + fg * 4 + r) * C_ + cb * 16 + fr], accB[cb][r]);

#pragma unroll
    for (int i = 0; i < 16; ++i) {
        float v = asum_reg[i];
        v += __shfl_xor(v, 1, 64); v += __shfl_xor(v, 2, 64);
        v += __shfl_xor(v, 4, 64); v += __shfl_xor(v, 8, 64);
        asum_reg[i] = v;
    }
    if (fr == 0) {
#pragma unroll
        for (int i = 0; i < 16; ++i) {
            int k = (i >> 2) * 16 + fg * 4 + (i & 3);
            atomicAdd(&ws[WS_ASUM + n * K_ + k], asum_reg[i] + 0.125f * (float)mcnt);
        }
    }
}

// per (n,k) row: subtract asum*centroid, intra-L2-normalize, accumulate gsum
__global__ void finalize_k(const float* __restrict__ cent, float* __restrict__ ws,
                           float* __restrict__ out) {
    int row = blockIdx.x * 4 + (threadIdx.x >> 6);  // n*64 + k
    int lane = threadIdx.x & 63;
    int n = row >> 6, k = row & 63;
    const float* v = ws + WS_VLAD + (size_t)row * C_;
    float as = ws[WS_ASUM + row];
    float y0 = v[lane] - as * cent[k * C_ + lane];
    float y1 = v[lane + 64] - as * cent[k * C_ + lane + 64];
    float ss = y0 * y0 + y1 * y1;
#pragma unroll
    for (int m = 1; m < 64; m <<= 1) ss += __shfl_xor(ss, m, 64);
    float rs = 1.0f / fmaxf(sqrtf(ss), 1e-12f);
    out[(size_t)row * C_ + lane] = y0 * rs;
    out[(size_t)row * C_ + lane + 64] = y1 * rs;
    if (lane == 0) atomicAdd(&ws[WS_GSUM + n], ss * rs * rs);
}

__global__ void gscale_k(float* __restrict__ out, const float* __restrict__ ws) {
    int idx = blockIdx.x * 256 + threadIdx.x;  // < N*K*C
    int n = idx >> 13;
    float g = ws[WS_GSUM + n];
    out[idx] *= 1.0f / fmaxf(sqrtf(g), 1e-12f);
}

extern "C" void kernel_launch(void* const* d_in, const int* in_sizes, int n_in,
                              void* d_out, int out_size, void* d_ws, size_t ws_size,
                              hipStream_t stream) {
    const float* x       = (const float*)d_in[0];
    const float* conv1_w = (const float*)d_in[1];
    const float* bn1_g   = (const float*)d_in[2];
    const float* bn1_b   = (const float*)d_in[3];
    const float* bn1_m   = (const float*)d_in[4];
    const float* bn1_v   = (const float*)d_in[5];
    const float* conv2_w = (const float*)d_in[6];
    const float* conv2_b = (const float*)d_in[7];
    const float* bn2_g   = (const float*)d_in[8];
    const float* bn2_b   = (const float*)d_in[9];
    const float* bn2_m   = (const float*)d_in[10];
    const float* bn2_v   = (const float*)d_in[11];
    const float* cent    = (const float*)d_in[12];
    const int*   length  = (const int*)d_in[13];
    float* out = (float*)d_out;
    float* ws  = (float*)d_ws;

    zero_ws<<<(WS_ZEND + 255) / 256, 256, 0, stream>>>(ws);
    setup_k<<<1, 256, 0, stream>>>(conv1_w, bn1_g, bn1_b, bn1_m, bn1_v,
                                   conv2_w, bn2_g, bn2_v, ws);
    rnorm_k<<<N_ * T_ / 4, 256, 0, stream>>>(x, ws);
    main_k<<<N_ * BPN, 256, 0, stream>>>(x, conv2_b, bn2_g, bn2_b, bn2_m, bn2_v,
                                         length, ws);
    finalize_k<<<(N_ * K_) / 4, 256, 0, stream>>>(cent, ws, out);
    gscale_k<<<(N_ * K_ * C_) / 256, 256, 0, stream>>>(out, ws);
}

// Round 7
// 136.503 us; speedup vs baseline: 2.0388x; 2.0388x over previous
//
#include <hip/hip_runtime.h>
#include <math.h>

#define N_ 16
#define T_ 8192
#define C_ 128
#define K_ 64

#define BPN 32    // blocks per n
#define TPB 256   // t per block
#define TILE 16   // t per wave-tile
#define SUP 64    // t per super-tile (4 waves x TILE)

// ws layout in floats (total ~4.46M floats = ~17.9 MB; assumes ws_size >= 18 MB)
#define WS_VLAD 0              // N*K*C = 131072
#define WS_ASUM 131072         // N*K
#define WS_GSUM 132096         // N
#define WS_ZEND 132608
#define WS_RNORM 132608        // N*T floats -> ends at 263680
#define WS_W2F   263680        // 4096 floats (8192 bf16 = w2 fragment table)
#define WS_P1    267776        // 512 floats (wa|wb|wc|sb, each [128])
#define WS_PART  268288        // N*BPN*K*C = 4194304 floats (per-block partials)

typedef __attribute__((ext_vector_type(8))) short short8;
typedef __attribute__((ext_vector_type(4))) float f32x4;

__device__ __forceinline__ uint bfr(float f) {          // fp32 -> bf16 (RNE)
    uint u = __float_as_uint(f);
    return (u + 0x7fffu + ((u >> 16) & 1u)) >> 16;
}
__device__ __forceinline__ float bflo(uint h) { return __uint_as_float(h << 16); }

__global__ void zero_ws(float* ws) {
    int i = blockIdx.x * 256 + threadIdx.x;
    if (i < WS_ZEND) ws[i] = 0.0f;
}

// Precompute constant tables, laid out for coalesced loads in main_k.
__global__ void setup_k(const float* __restrict__ conv1_w,
                        const float* __restrict__ bn1_g, const float* __restrict__ bn1_b,
                        const float* __restrict__ bn1_m, const float* __restrict__ bn1_v,
                        const float* __restrict__ conv2_w,
                        const float* __restrict__ bn2_g, const float* __restrict__ bn2_v,
                        float* __restrict__ ws) {
    const int tid = threadIdx.x;
    // w2 fragment table: idx = ((m*4+q)*64 + lane)*8 + j
    ushort* w2t = (ushort*)(ws + WS_W2F);
    for (int idx = tid; idx < 8192; idx += 256) {
        int j = idx & 7;
        int lane = (idx >> 3) & 63;
        int mq = idx >> 9;                  // 0..15
        int m = mq >> 2, q = mq & 3;
        int fr = lane & 15, fg = lane >> 4;
        int k = m * 16 + fr;
        float sck = bn2_g[k] * rsqrtf(bn2_v[k] + 1e-5f);
        float v = conv2_w[k * C_ + q * 32 + fg * 8 + j] * sck;
        w2t[idx] = (ushort)bfr(v);
    }
    // conv1/bn1 folded params, [param][c]
    for (int c = tid; c < C_; c += 256) {
        float s1 = bn1_g[c] * rsqrtf(bn1_v[c] + 1e-5f);
        ws[WS_P1 + c]       = conv1_w[c * 9 + 1] * s1;
        ws[WS_P1 + 128 + c] = conv1_w[c * 9 + 4] * s1;
        ws[WS_P1 + 256 + c] = conv1_w[c * 9 + 7] * s1;
        ws[WS_P1 + 384 + c] = bn1_b[c] - bn1_m[c] * s1;
    }
}

// 1 / max(||x[n,t,:]||, 1e-12), one wave per (n,t) row
__global__ void rnorm_k(const float* __restrict__ x, float* __restrict__ ws) {
    int row = blockIdx.x * 4 + (threadIdx.x >> 6);
    int lane = threadIdx.x & 63;
    const float* xr = x + (size_t)row * C_;
    float a = xr[lane], b = xr[lane + 64];
    float ss = a * a + b * b;
#pragma unroll
    for (int m = 1; m < 64; m <<= 1) ss += __shfl_xor(ss, m, 64);
    if (lane == 0) ws[WS_RNORM + row] = 1.0f / fmaxf(sqrtf(ss), 1e-12f);
}

// Fused: normalize -> dwconv3+bn1+relu -> logits (MFMA) -> bn2+relu+mask
// -> softmax -> vlad GEMM (MFMA, bf16 a/xn, fp32 acc) -> PRIVATE partial store.
__global__ __launch_bounds__(256, 2) void main_k(
    const float* __restrict__ x,
    const float* __restrict__ conv2_b,
    const float* __restrict__ bn2_g, const float* __restrict__ bn2_b,
    const float* __restrict__ bn2_m, const float* __restrict__ bn2_v,
    const int* __restrict__ length,
    float* __restrict__ ws) {

    // h: per-wave [16t][136c-pad] bf16 rows (272B, 16B-aligned)
    __shared__ __align__(16) ushort h_s[4][TILE * 136];      // 17408 B
    // xn/a: t-minor, 16B chunks, XOR-swizzled: chunk(row,j) = row*8 + (j^(row&7))
    __shared__ __align__(16) uint4 xn4[C_ * 8];              // 16384 B
    __shared__ __align__(16) ushort a_s[K_ * 64];            // 8192 B
    __shared__ float rn_lds[TPB + 2];

    const int tid = threadIdx.x;
    const int lane = tid & 63;
    const int w = tid >> 6;
    const int fr = lane & 15, fg = lane >> 4;
    const int n = blockIdx.x >> 5;                 // / BPN
    const int chunk = blockIdx.x & (BPN - 1);
    const int tb = chunk * TPB;
    const float* xb = x + (size_t)n * T_ * C_;
    const float* rng = ws + WS_RNORM + (size_t)n * T_;
    const int L = length[n];

    for (int i = tid; i < TPB + 2; i += 256) {
        int t = tb - 1 + i;
        rn_lds[i] = (t >= 0 && t < T_) ? rng[t] : 0.f;
    }

    // conv1/bn1 folded params for c = lane, lane+64 (coalesced table loads)
    float wa[2], wbv[2], wcv[2], sbv[2];
#pragma unroll
    for (int p = 0; p < 2; ++p) {
        int c = lane + p * 64;
        wa[p]  = ws[WS_P1 + c];
        wbv[p] = ws[WS_P1 + 128 + c];
        wcv[p] = ws[WS_P1 + 256 + c];
        sbv[p] = ws[WS_P1 + 384 + c];
    }

    // w2 A-fragments from precomputed table (coalesced b128 loads)
    const ushort* w2t = (const ushort*)(ws + WS_W2F);
    short8 w2h[4][4];
#pragma unroll
    for (int m = 0; m < 4; ++m)
#pragma unroll
        for (int q = 0; q < 4; ++q)
            w2h[m][q] = *(const short8*)&w2t[((m * 4 + q) * 64 + lane) * 8];

    // bias in softmax register layout: k = m*16 + fg*4 + r
    float sh2r[16];
#pragma unroll
    for (int m = 0; m < 4; ++m)
#pragma unroll
        for (int r = 0; r < 4; ++r) {
            int k = m * 16 + fg * 4 + r;
            float s = bn2_g[k] * rsqrtf(bn2_v[k] + 1e-5f);
            sh2r[m * 4 + r] = s * conv2_b[k] + bn2_b[k] - bn2_m[k] * s;
        }

    f32x4 accB[8];
#pragma unroll
    for (int cb = 0; cb < 8; ++cb) accB[cb] = (f32x4){0.f, 0.f, 0.f, 0.f};
    float asum_reg[16];
#pragma unroll
    for (int i = 0; i < 16; ++i) asum_reg[i] = 0.f;
    int mcnt = 0;

    __syncthreads();

    for (int s = 0; s < TPB / SUP; ++s) {
        const int t0 = tb + s * SUP + w * TILE;
        const bool full = (t0 < L);
        const int tl0 = t0 - tb;
        ushort* hw = h_s[w];

        // ---- A1: rolling 3-tap conv along t, lane = channel ----
#pragma unroll
        for (int p = 0; p < 2; ++p) {
            const int c = lane + p * 64;
            float xnm = 0.f;
            if (t0 > 0) xnm = xb[(size_t)(t0 - 1) * C_ + c] * rn_lds[tl0];
            float xnc = xb[(size_t)t0 * C_ + c] * rn_lds[tl0 + 1];
            uint pk[8];
#pragma unroll
            for (int tl = 0; tl < TILE; ++tl) {
                int tn = t0 + tl + 1;
                float xnp = 0.f;
                if (tn < T_) xnp = xb[(size_t)tn * C_ + c] * rn_lds[tl0 + tl + 2];
                if (full) {
                    float h = fmaxf(0.f, xnm * wa[p] + xnc * wbv[p] + xnp * wcv[p] + sbv[p]);
                    hw[tl * 136 + c] = (ushort)bfr(h);
                }
                uint b = bfr(xnc);
                if (tl & 1) pk[tl >> 1] |= b << 16; else pk[tl >> 1] = b;
                xnm = xnc; xnc = xnp;
            }
            uint4 lo4, hi4;
            lo4.x = pk[0]; lo4.y = pk[1]; lo4.z = pk[2]; lo4.w = pk[3];
            hi4.x = pk[4]; hi4.y = pk[5]; hi4.z = pk[6]; hi4.w = pk[7];
            xn4[c * 8 + ((w * 2) ^ (c & 7))] = lo4;
            xn4[c * 8 + ((w * 2 + 1) ^ (c & 7))] = hi4;
        }

        if (full) {
            // ---- logits MFMA: S[k][t] = sum_c w2'[k][c] h[t][c] ----
            f32x4 accL[4];
#pragma unroll
            for (int m = 0; m < 4; ++m) accL[m] = (f32x4){0.f, 0.f, 0.f, 0.f};
            const ushort* hb = hw + fr * 136 + fg * 8;
#pragma unroll
            for (int q = 0; q < 4; ++q) {
                short8 hf = *(const short8*)(hb + q * 32);
                accL[0] = __builtin_amdgcn_mfma_f32_16x16x32_bf16(w2h[0][q], hf, accL[0], 0, 0, 0);
                accL[1] = __builtin_amdgcn_mfma_f32_16x16x32_bf16(w2h[1][q], hf, accL[1], 0, 0, 0);
                accL[2] = __builtin_amdgcn_mfma_f32_16x16x32_bf16(w2h[2][q], hf, accL[2], 0, 0, 0);
                accL[3] = __builtin_amdgcn_mfma_f32_16x16x32_bf16(w2h[3][q], hf, accL[3], 0, 0, 0);
            }
            // ---- bn2 + relu + mask + softmax over k (this lane: t = t0+fr) ----
            int t = t0 + fr;
            float v[16];
#pragma unroll
            for (int m = 0; m < 4; ++m)
#pragma unroll
                for (int r = 0; r < 4; ++r)
                    v[m * 4 + r] = fmaxf(0.f, accL[m][r] + sh2r[m * 4 + r]);
            if (t < L) {
                float mx = v[0];
#pragma unroll
                for (int i = 1; i < 16; ++i) mx = fmaxf(mx, v[i]);
                mx = fmaxf(mx, __shfl_xor(mx, 16, 64));
                mx = fmaxf(mx, __shfl_xor(mx, 32, 64));
                float se = 0.f;
#pragma unroll
                for (int i = 0; i < 16; ++i) { v[i] = __expf(v[i] - mx); se += v[i]; }
                se += __shfl_xor(se, 16, 64);
                se += __shfl_xor(se, 32, 64);
                float inv = 1.0f / se;
#pragma unroll
                for (int i = 0; i < 16; ++i) v[i] *= inv;
            } else {
#pragma unroll
                for (int i = 0; i < 16; ++i) v[i] = 0.015625f;
            }
            // write a (bf16) t-minor + accumulate rounded asum
            const int jq = w * 2 + (fr >> 3);
            const int te = fr & 7;
#pragma unroll
            for (int m = 0; m < 4; ++m)
#pragma unroll
                for (int r = 0; r < 4; ++r) {
                    int k = m * 16 + fg * 4 + r;
                    uint hv = bfr(v[m * 4 + r]);
                    a_s[(k * 8 + (jq ^ (k & 7))) * 8 + te] = (ushort)hv;
                    asum_reg[m * 4 + r] += bflo(hv);
                }
        } else {
            // fully masked tile: a = 1/64 (bf16 exact)
            uint4 ones;
            ones.x = ones.y = ones.z = ones.w = 0x3C803C80u;
            *(uint4*)&a_s[(lane * 8 + ((w * 2) ^ (lane & 7))) * 8] = ones;
            *(uint4*)&a_s[(lane * 8 + ((w * 2 + 1) ^ (lane & 7))) * 8] = ones;
            mcnt++;
        }
        __syncthreads();

        // ---- phase B: vlad GEMM on MFMA. wave w owns k-block w ----
#pragma unroll
        for (int tK = 0; tK < 2; ++tK) {
            int ar = w * 16 + fr;
            short8 af = *(const short8*)&a_s[(ar * 8 + ((tK * 4 + fg) ^ (ar & 7))) * 8];
#pragma unroll
            for (int cb = 0; cb < 8; ++cb) {
                int cr = cb * 16 + fr;
                short8 bf = *(const short8*)&xn4[cr * 8 + ((tK * 4 + fg) ^ (cr & 7))];
                accB[cb] = __builtin_amdgcn_mfma_f32_16x16x32_bf16(af, bf, accB[cb], 0, 0, 0);
            }
        }
        __syncthreads();
    }

    // ---- private partial store (NO vlad atomics) ----
    float* part = ws + WS_PART + (size_t)(n * BPN + chunk) * (K_ * C_);
#pragma unroll
    for (int cb = 0; cb < 8; ++cb)
#pragma unroll
        for (int r = 0; r < 4; ++r)
            part[(w * 16 + fg * 4 + r) * C_ + cb * 16 + fr] = accB[cb][r];

#pragma unroll
    for (int i = 0; i < 16; ++i) {
        float v = asum_reg[i];
        v += __shfl_xor(v, 1, 64); v += __shfl_xor(v, 2, 64);
        v += __shfl_xor(v, 4, 64); v += __shfl_xor(v, 8, 64);
        asum_reg[i] = v;
    }
    if (fr == 0) {
#pragma unroll
        for (int i = 0; i < 16; ++i) {
            int k = (i >> 2) * 16 + fg * 4 + (i & 3);
            atomicAdd(&ws[WS_ASUM + n * K_ + k], asum_reg[i] + 0.25f * (float)mcnt);
        }
    }
}

// vlad[n][k][c] = sum over BPN per-block partials
__global__ void reduce_k(float* __restrict__ ws) {
    int idx = blockIdx.x * 256 + threadIdx.x;      // < N*K*C
    int n = idx >> 13;
    const float* p = ws + WS_PART + (size_t)n * BPN * (K_ * C_) + (idx & 8191);
    float s = 0.f;
#pragma unroll 8
    for (int b = 0; b < BPN; ++b) s += p[(size_t)b * (K_ * C_)];
    ws[WS_VLAD + idx] = s;
}

// per (n,k) row: subtract asum*centroid, intra-L2-normalize, accumulate gsum
__global__ void finalize_k(const float* __restrict__ cent, float* __restrict__ ws,
                           float* __restrict__ out) {
    int row = blockIdx.x * 4 + (threadIdx.x >> 6);  // n*64 + k
    int lane = threadIdx.x & 63;
    int n = row >> 6, k = row & 63;
    const float* v = ws + WS_VLAD + (size_t)row * C_;
    float as = ws[WS_ASUM + row];
    float y0 = v[lane] - as * cent[k * C_ + lane];
    float y1 = v[lane + 64] - as * cent[k * C_ + lane + 64];
    float ss = y0 * y0 + y1 * y1;
#pragma unroll
    for (int m = 1; m < 64; m <<= 1) ss += __shfl_xor(ss, m, 64);
    float rs = 1.0f / fmaxf(sqrtf(ss), 1e-12f);
    out[(size_t)row * C_ + lane] = y0 * rs;
    out[(size_t)row * C_ + lane + 64] = y1 * rs;
    if (lane == 0) atomicAdd(&ws[WS_GSUM + n], ss * rs * rs);
}

__global__ void gscale_k(float* __restrict__ out, const float* __restrict__ ws) {
    int idx = blockIdx.x * 256 + threadIdx.x;  // < N*K*C
    int n = idx >> 13;
    float g = ws[WS_GSUM + n];
    out[idx] *= 1.0f / fmaxf(sqrtf(g), 1e-12f);
}

extern "C" void kernel_launch(void* const* d_in, const int* in_sizes, int n_in,
                              void* d_out, int out_size, void* d_ws, size_t ws_size,
                              hipStream_t stream) {
    const float* x       = (const float*)d_in[0];
    const float* conv1_w = (const float*)d_in[1];
    const float* bn1_g   = (const float*)d_in[2];
    const float* bn1_b   = (const float*)d_in[3];
    const float* bn1_m   = (const float*)d_in[4];
    const float* bn1_v   = (const float*)d_in[5];
    const float* conv2_w = (const float*)d_in[6];
    const float* conv2_b = (const float*)d_in[7];
    const float* bn2_g   = (const float*)d_in[8];
    const float* bn2_b   = (const float*)d_in[9];
    const float* bn2_m   = (const float*)d_in[10];
    const float* bn2_v   = (const float*)d_in[11];
    const float* cent    = (const float*)d_in[12];
    const int*   length  = (const int*)d_in[13];
    float* out = (float*)d_out;
    float* ws  = (float*)d_ws;

    zero_ws<<<(WS_ZEND + 255) / 256, 256, 0, stream>>>(ws);
    setup_k<<<1, 256, 0, stream>>>(conv1_w, bn1_g, bn1_b, bn1_m, bn1_v,
                                   conv2_w, bn2_g, bn2_v, ws);
    rnorm_k<<<N_ * T_ / 4, 256, 0, stream>>>(x, ws);
    main_k<<<N_ * BPN, 256, 0, stream>>>(x, conv2_b, bn2_g, bn2_b, bn2_m, bn2_v,
                                         length, ws);
    reduce_k<<<(N_ * K_ * C_) / 256, 256, 0, stream>>>(ws);
    finalize_k<<<(N_ * K_) / 4, 256, 0, stream>>>(cent, ws, out);
    gscale_k<<<(N_ * K_ * C_) / 256, 256, 0, stream>>>(out, ws);
}